// Round 1
// baseline (3410.820 us; speedup 1.0000x reference)
//
#include <hip/hip_runtime.h>

// Fused persistent RNN encoder:
//   h_{t+1} = relu([x_t | h_t] @ W^T + b)  -- one K=2048 GEMM per step, W in its
//   natural [1024][2048] layout (cast to bf16 once). No Z materialization.
// One cooperative kernel, 256 blocks (1/CU), grid barrier between steps.
// Block tile 128x128, 8 waves = 4 spatial (64x64) x 2 kq-groups (K-split),
// LDS double-buffered, XOR-swizzled (chunk ^ (row&7)). Fallback: per-step launches.

typedef __bf16 bf16;
typedef __bf16 bf16x8 __attribute__((ext_vector_type(8)));
typedef __bf16 bf16x4 __attribute__((ext_vector_type(4)));
typedef float f32x4 __attribute__((ext_vector_type(4)));

#define B_N 4096
#define T_N 35
#define U_N 1024
#define K2 2048
#define XROW (T_N * U_N)

#define AS1CP(p) ((const __attribute__((address_space(1))) void*)(p))
#define AS3CP(p) ((__attribute__((address_space(3))) void*)(p))

// ---- pack W (1024 x 2048 fp32) -> Wb (1024 x 2048 bf16, same layout) ----
__global__ __launch_bounds__(256) void pack_w(const float* __restrict__ W,
                                              bf16* __restrict__ Wb) {
  int i = (blockIdx.x * 256 + threadIdx.x) * 4;  // over 1024*2048
  f32x4 a = *(const f32x4*)(W + i);
  bf16x4 v = { (bf16)a.x, (bf16)a.y, (bf16)a.z, (bf16)a.w };
  *(bf16x4*)(Wb + i) = v;
}

// ---- persistent fused kernel ----
// grid 256 blocks x 512 threads. Block (rg,cg): rows rg*128..+128, cols cg*128..+128.
// XCD-local mapping: L&7 = xcd hosts rgs xcd*4..+4 (all 8 cgs of each rg co-XCD).
__global__ __launch_bounds__(512, 1) void rnn_fused(
    const float* __restrict__ x, const bf16* __restrict__ Wb,
    const float* __restrict__ bias, bf16* __restrict__ hA,
    bf16* __restrict__ hB, float* __restrict__ out,
    unsigned* __restrict__ bar, int t0, int t1)
{
  __shared__ __align__(16) bf16 smem[2][2][128 * 64];  // [buf][A=0/B=1], 64 KB

  const int tid = threadIdx.x;
  const int w = tid >> 6, l = tid & 63;
  const int L = blockIdx.x;
  const int rg = (L & 7) * 4 + ((L >> 3) >> 3);  // 0..31
  const int cg = (L >> 3) & 7;                   // 0..7
  const int r0 = rg << 7;
  const int c0 = cg << 7;

  const int s = w & 3;   // spatial wave: 2x2 over 128x128
  const int g = w >> 2;  // kq group (K-split)
  const int wm = s & 1, wn = s >> 1;
  const int lq = l >> 4, lm = l & 15;
  const int lrow8 = l >> 3;
  const int clog = (l & 7) ^ lrow8;  // logical chunk fetched by this lane

  // x reg-staging assignment: 4 threads/row, 16 floats each
  const int xrow = tid >> 2;   // 0..127
  const int xc2 = tid & 3;     // 16-float chunk
  const float* xrowp = x + (size_t)(r0 + xrow) * XROW + xc2 * 16;

  float bv[4];
#pragma unroll
  for (int ni = 0; ni < 4; ++ni) bv[ni] = bias[c0 + wn * 64 + ni * 16 + lm];

  for (int t = t0; t < t1; ++t) {
    const bf16* hin = (t & 1) ? hB : hA;
    bf16* hout = (t & 1) ? hA : hB;
    const int kend = (t == 0) ? 1024 : K2;  // t=0: h is zero, skip h half
    const float* xb = xrowp + (size_t)t * U_N;

    f32x4 acc[4][4] = {};

    // ---- prologue: stage kk=0 (B via async, A=x via reg) into buf 0 ----
#pragma unroll
    for (int r = 0; r < 2; ++r) {
      int nr = w * 16 + r * 8;
      const bf16* gb = Wb + (size_t)(c0 + nr + lrow8) * K2 + clog * 8;
      __builtin_amdgcn_global_load_lds(AS1CP(gb), AS3CP(&smem[0][1][nr * 64]), 16, 0, 0);
    }
    {
      f32x4 f0 = *(const f32x4*)(xb);
      f32x4 f1 = *(const f32x4*)(xb + 4);
      f32x4 f2 = *(const f32x4*)(xb + 8);
      f32x4 f3 = *(const f32x4*)(xb + 12);
      bf16x8 v0 = { (bf16)f0.x, (bf16)f0.y, (bf16)f0.z, (bf16)f0.w,
                    (bf16)f1.x, (bf16)f1.y, (bf16)f1.z, (bf16)f1.w };
      bf16x8 v1 = { (bf16)f2.x, (bf16)f2.y, (bf16)f2.z, (bf16)f2.w,
                    (bf16)f3.x, (bf16)f3.y, (bf16)f3.z, (bf16)f3.w };
      *(bf16x8*)(&smem[0][0][xrow * 64 + (((xc2 << 1) ^ (xrow & 7)) << 3)]) = v0;
      *(bf16x8*)(&smem[0][0][xrow * 64 + ((((xc2 << 1) | 1) ^ (xrow & 7)) << 3)]) = v1;
    }
    __syncthreads();

    int cur = 0;
    for (int kk = 0; kk < kend; kk += 64) {
      const int nkk = kk + 64;
      const bool hasnext = nkk < kend;
      const bool nx = hasnext && (nkk < 1024);   // next tile from x (fp32)
      const bool nh = hasnext && (nkk >= 1024);  // next tile from h (bf16)
      const int nxt = cur ^ 1;

      // T14 split: issue x loads early, convert+write after MFMAs
      f32x4 f0, f1, f2, f3;
      if (nx) {
        const float* gx = xb + nkk;
        f0 = *(const f32x4*)(gx);
        f1 = *(const f32x4*)(gx + 4);
        f2 = *(const f32x4*)(gx + 8);
        f3 = *(const f32x4*)(gx + 12);
      }
      if (hasnext) {
#pragma unroll
        for (int r = 0; r < 2; ++r) {
          int nr = w * 16 + r * 8;
          const bf16* gb = Wb + (size_t)(c0 + nr + lrow8) * K2 + nkk + clog * 8;
          __builtin_amdgcn_global_load_lds(AS1CP(gb), AS3CP(&smem[nxt][1][nr * 64]), 16, 0, 0);
        }
      }
      if (nh) {
#pragma unroll
        for (int r = 0; r < 2; ++r) {
          int nr = w * 16 + r * 8;
          const bf16* gh = hin + (size_t)(r0 + nr + lrow8) * U_N + (nkk - 1024) + clog * 8;
          __builtin_amdgcn_global_load_lds(AS1CP(gh), AS3CP(&smem[nxt][0][nr * 64]), 16, 0, 0);
        }
      }

      // compute buf cur: this wave's kq = g only (K-split across wave groups)
      {
        const bf16* As = &smem[cur][0][0];
        const bf16* Bs = &smem[cur][1][0];
        bf16x8 af[4], bfr[4];
#pragma unroll
        for (int mi = 0; mi < 4; ++mi) {
          int r = wm * 64 + mi * 16 + lm;
          af[mi] = *(const bf16x8*)(As + r * 64 + ((((g << 2) + lq) ^ (r & 7)) << 3));
        }
#pragma unroll
        for (int ni = 0; ni < 4; ++ni) {
          int c = wn * 64 + ni * 16 + lm;
          bfr[ni] = *(const bf16x8*)(Bs + c * 64 + ((((g << 2) + lq) ^ (c & 7)) << 3));
        }
#pragma unroll
        for (int mi = 0; mi < 4; ++mi)
#pragma unroll
          for (int ni = 0; ni < 4; ++ni)
            acc[mi][ni] = __builtin_amdgcn_mfma_f32_16x16x32_bf16(af[mi], bfr[ni],
                                                                  acc[mi][ni], 0, 0, 0);
      }

      if (nx) {
        bf16x8 v0 = { (bf16)f0.x, (bf16)f0.y, (bf16)f0.z, (bf16)f0.w,
                      (bf16)f1.x, (bf16)f1.y, (bf16)f1.z, (bf16)f1.w };
        bf16x8 v1 = { (bf16)f2.x, (bf16)f2.y, (bf16)f2.z, (bf16)f2.w,
                      (bf16)f3.x, (bf16)f3.y, (bf16)f3.z, (bf16)f3.w };
        *(bf16x8*)(&smem[nxt][0][xrow * 64 + (((xc2 << 1) ^ (xrow & 7)) << 3)]) = v0;
        *(bf16x8*)(&smem[nxt][0][xrow * 64 + ((((xc2 << 1) | 1) ^ (xrow & 7)) << 3)]) = v1;
      }
      __syncthreads();
      cur = nxt;
    }

    // ---- reduce kq-group 1 into group 0 via LDS (reuse smem, conflict-free) ----
    float* red = (float*)&smem[0][0][0];
    if (g == 1) {
#pragma unroll
      for (int mi = 0; mi < 4; ++mi)
#pragma unroll
        for (int ni = 0; ni < 4; ++ni)
          *(f32x4*)(red + (size_t)(s * 16 + mi * 4 + ni) * 256 + l * 4) = acc[mi][ni];
    }
    __syncthreads();
    if (g == 0) {
#pragma unroll
      for (int mi = 0; mi < 4; ++mi)
#pragma unroll
        for (int ni = 0; ni < 4; ++ni)
          acc[mi][ni] += *(const f32x4*)(red + (size_t)(s * 16 + mi * 4 + ni) * 256 + l * 4);

      // epilogue: h' = relu(acc + b); final step also writes fp32 out
#pragma unroll
      for (int ni = 0; ni < 4; ++ni) {
        int col = c0 + wn * 64 + ni * 16 + lm;
#pragma unroll
        for (int mi = 0; mi < 4; ++mi) {
          int rbase = r0 + wm * 64 + mi * 16 + lq * 4;
#pragma unroll
          for (int i = 0; i < 4; ++i) {
            float v = acc[mi][ni][i] + bv[ni];
            v = v > 0.f ? v : 0.f;
            hout[(size_t)(rbase + i) * U_N + col] = (bf16)v;
            if (t == T_N - 1) out[(size_t)(rbase + i) * U_N + col] = v;
          }
        }
      }
    }

    // ---- device-scope grid barrier between steps (skipped in fallback mode) ----
    if (t + 1 < t1) {
      __syncthreads();
      if (tid == 0) {
        __threadfence();                 // release: flush h writes past L2
        atomicAdd(bar, 1u);
        unsigned tgt = (unsigned)(t + 1 - t0) * 256u;
        while (atomicAdd(bar, 0u) < tgt) __builtin_amdgcn_s_sleep(2);
      }
      __syncthreads();
      __threadfence();                   // acquire: invalidate stale h lines
    }
  }
}

extern "C" void kernel_launch(void* const* d_in, const int* in_sizes, int n_in,
                              void* d_out, int out_size, void* d_ws, size_t ws_size,
                              hipStream_t stream) {
  const float* x    = (const float*)d_in[0];
  const float* W    = (const float*)d_in[1];
  const float* bias = (const float*)d_in[2];
  float* out = (float*)d_out;

  char* ws = (char*)d_ws;
  bf16* Wb = (bf16*)ws;                                  // 4 MB
  bf16* hA = (bf16*)(ws + ((size_t)4 << 20));            // 8 MB
  bf16* hB = (bf16*)(ws + ((size_t)12 << 20));           // 8 MB
  unsigned* bar = (unsigned*)(ws + ((size_t)20 << 20));  // 4 B

  pack_w<<<2048, 256, 0, stream>>>(W, Wb);
  hipMemsetAsync(bar, 0, sizeof(unsigned), stream);

  int t0 = 0, t1 = T_N;
  void* args[] = { (void*)&x, (void*)&Wb, (void*)&bias, (void*)&hA, (void*)&hB,
                   (void*)&out, (void*)&bar, (void*)&t0, (void*)&t1 };
  hipError_t err = hipLaunchCooperativeKernel((const void*)rnn_fused, dim3(256),
                                              dim3(512), args, 0, stream);
  if (err != hipSuccess) {
    // fallback: per-step launches; barrier is statically skipped (t1 == t0+1)
    (void)hipGetLastError();
    for (int t = 0; t < T_N; ++t)
      rnn_fused<<<dim3(256), dim3(512), 0, stream>>>(x, Wb, bias, hA, hB, out,
                                                     bar, t, t + 1);
  }
}